// Round 5
// baseline (328.231 us; speedup 1.0000x reference)
//
#include <hip/hip_runtime.h>
#include <hip/hip_bf16.h>
#include <math.h>

typedef float v4f __attribute__((ext_vector_type(4)));
typedef __bf16 bf16x8 __attribute__((ext_vector_type(8)));

#define NN   1024
#define INF  128
#define H0C  192
#define H1C  96

// ws byte offsets
#define WS_W0BF   0        // 24576 bf16 = 49152 B (16x16x32 B-frag order, BN0 scale folded)
#define WS_W1BF   49152    // 18432 bf16 = 36864 B (16x16x32 B-frag order, BN1 scale folded)
#define WS_BN0B   86016    // 192 f32 folded bias
#define WS_BN1B   86784    // 96 f32 folded bias
#define WS_WOUT   87168    // 96 f32
#define WS_CSUM   87552    // 1024 f32 column sums (atomic)

// ---------------------------------------------------------------------------
// Prep: swizzle weights into MFMA B-fragment order (bf16), BN scale folded,
// bias folded separately; zero the colsum accumulator (ws is poisoned 0xAA
// before every launch).
// B-frag (16x16x32): lane holds B[k=quad*8+j][n=lane&15],
// flat [(ntile*KS+ks)*64 + lane]*8 + j.   [validated round 2]
// ---------------------------------------------------------------------------
__global__ __launch_bounds__(256) void prep_kernel(
    const float* __restrict__ W0, const float* __restrict__ g0,
    const float* __restrict__ b0, const float* __restrict__ m0,
    const float* __restrict__ v0, const float* __restrict__ W1,
    const float* __restrict__ g1, const float* __restrict__ b1,
    const float* __restrict__ m1, const float* __restrict__ v1,
    const float* __restrict__ Wout, char* __restrict__ ws)
{
    int e = blockIdx.x * 256 + threadIdx.x;
    __bf16* w0bf = (__bf16*)(ws + WS_W0BF);
    __bf16* w1bf = (__bf16*)(ws + WS_W1BF);
    float* bn0b = (float*)(ws + WS_BN0B);
    float* bn1b = (float*)(ws + WS_BN1B);
    float* wout = (float*)(ws + WS_WOUT);
    float* csum = (float*)(ws + WS_CSUM);
    if (e < 24576) {                       // W0: 12 ntiles x 4 ksteps
        int j = e & 7, lane = (e >> 3) & 63, t = e >> 9;
        int ks = t & 3, nt = t >> 2;
        int c = nt * 16 + (lane & 15);               // n = H0 channel
        int k = ks * 32 + ((lane >> 4) << 3) + j;    // k = input feature
        float s = g0[c] * rsqrtf(v0[c] + 1e-5f);
        w0bf[e] = (__bf16)(W0[c * INF + k] * s);
    } else if (e < 43008) {                // W1: 6 ntiles x 6 ksteps
        int e2 = e - 24576;
        int j = e2 & 7, lane = (e2 >> 3) & 63, t = e2 >> 9;
        int ks = t % 6, nt = t / 6;
        int c = nt * 16 + (lane & 15);               // n = H1 channel
        int k = ks * 32 + ((lane >> 4) << 3) + j;    // k = H0 channel
        float s = g1[c] * rsqrtf(v1[c] + 1e-5f);
        w1bf[e2] = (__bf16)(W1[c * H0C + k] * s);
    } else if (e < 43200) {                // BN0 folded bias
        int c = e - 43008;
        float s = g0[c] * rsqrtf(v0[c] + 1e-5f);
        bn0b[c] = b0[c] - m0[c] * s;
    } else if (e < 43296) {                // BN1 folded bias
        int c = e - 43200;
        float s = g1[c] * rsqrtf(v1[c] + 1e-5f);
        bn1b[c] = b1[c] - m1[c] * s;
    } else if (e < 43392) {                // Wout copy
        wout[e - 43296] = Wout[e - 43296];
    } else if (e < 44416) {                // zero colsum
        csum[e - 43392] = 0.f;
    }
}

// ---------------------------------------------------------------------------
// Main fused kernel. Block = 4 waves, tile 16 i x 8 j = 128 pairs; wave w
// owns j-columns jb=8bj+2w, jb+1 (32 pairs, M=2 mtiles of 16).
// - X fragments generated directly in registers (no X LDS, phase/barriers).
// - GEMM1 split into two 96-channel halves (acc1 = 48 regs, not 96).
// - H0 half round-trips through WAVE-PRIVATE LDS (32 x 104 bf16, 6.5 KB/wave)
//   to transpose C-layout -> A-frag; K=32 MFMA for BOTH layers.
// - __syncthreads() per half = rhythm barrier: keeps the 4 waves' identical
//   weight-load streams time-coalesced so L1 serves repeats (R2 evidence:
//   barrier kernels beat barrier-free on the same L2 traffic).
// - Epilogue fuses column-sum via atomics (direct/mirror dedup predicate).
// Symmetry: triangular tiles bj >= 2*bi (4160 blocks); writes sim[i][j] and
// sim[j][i].
// ---------------------------------------------------------------------------
__global__ __launch_bounds__(256, 3) void edgenet_main(
    const float* __restrict__ feat, const char* __restrict__ ws,
    const float* __restrict__ boutp, float* __restrict__ sim_out,
    float* __restrict__ colsum)
{
    __shared__ __align__(16) char smem[26624];   // 4 waves * 32 rows * 208 B
    const int tid = threadIdx.x;
    const int lane = tid & 63;
    const int wave = tid >> 6;
    const int l16 = lane & 15;
    const int quad = lane >> 4;

    // decode triangular tile id -> (bi, bj): cum(bi) = bi*(129-bi)  [R2-verified]
    const int id = blockIdx.x;
    int bi = (int)((129.0f - sqrtf(16641.0f - 4.0f * (float)id)) * 0.5f);
    while (bi > 0 && bi * (129 - bi) > id) --bi;
    while ((bi + 1) * (128 - bi) <= id) ++bi;
    const int bj = 2 * bi + (id - bi * (129 - bi));
    const int i0 = bi << 4;
    const int jb = (bj << 3) + wave * 2;
    char* hbase = smem + wave * 6656;

    // ---- X A-fragments in registers: xf[mt][ks], lane = X[pair=l16][32ks+8q+j]
    bf16x8 xf[2][4];
    #pragma unroll
    for (int ks = 0; ks < 4; ++ks) {
        const float* fi = feat + (i0 + l16) * INF + ks * 32 + quad * 8;
        float4 a0 = *(const float4*)fi;
        float4 a1 = *(const float4*)(fi + 4);
        #pragma unroll
        for (int mt = 0; mt < 2; ++mt) {
            const float* fj = feat + (jb + mt) * INF + ks * 32 + quad * 8;
            float4 q0 = *(const float4*)fj;
            float4 q1 = *(const float4*)(fj + 4);
            bf16x8 x;
            x[0] = (__bf16)fabsf(a0.x - q0.x);
            x[1] = (__bf16)fabsf(a0.y - q0.y);
            x[2] = (__bf16)fabsf(a0.z - q0.z);
            x[3] = (__bf16)fabsf(a0.w - q0.w);
            x[4] = (__bf16)fabsf(a1.x - q1.x);
            x[5] = (__bf16)fabsf(a1.y - q1.y);
            x[6] = (__bf16)fabsf(a1.z - q1.z);
            x[7] = (__bf16)fabsf(a1.w - q1.w);
            xf[mt][ks] = x;
        }
    }

    const bf16x8* w0v = (const bf16x8*)(ws + WS_W0BF);
    const bf16x8* w1v = (const bf16x8*)(ws + WS_W1BF);
    const float* bn0b = (const float*)(ws + WS_BN0B);
    const float* bn1b = (const float*)(ws + WS_BN1B);

    // ---- acc2 init with bn1 bias (col = ch_out = 16nt2+l16, bcast over rows)
    v4f acc2[2][6];
    #pragma unroll
    for (int nt2 = 0; nt2 < 6; ++nt2) {
        float bb = bn1b[nt2 * 16 + l16];
        acc2[0][nt2] = (v4f){bb, bb, bb, bb};
        acc2[1][nt2] = acc2[0][nt2];
    }

    // ---- two 96-channel halves: GEMM1-half -> leaky -> LDS -> GEMM2-half ----
    #pragma unroll 1
    for (int h = 0; h < 2; ++h) {
        // GEMM1 half: channels [96h, 96h+96)
        v4f acc1[2][6];
        #pragma unroll
        for (int nt = 0; nt < 6; ++nt) {
            float bb = bn0b[h * 96 + nt * 16 + l16];
            v4f c0 = (v4f){bb, bb, bb, bb};
            bf16x8 w = w0v[((h * 6 + nt) * 4 + 0) * 64 + lane];
            acc1[0][nt] = __builtin_amdgcn_mfma_f32_16x16x32_bf16(xf[0][0], w, c0, 0, 0, 0);
            acc1[1][nt] = __builtin_amdgcn_mfma_f32_16x16x32_bf16(xf[1][0], w, c0, 0, 0, 0);
            #pragma unroll
            for (int ks = 1; ks < 4; ++ks) {
                bf16x8 w2 = w0v[((h * 6 + nt) * 4 + ks) * 64 + lane];
                acc1[0][nt] = __builtin_amdgcn_mfma_f32_16x16x32_bf16(xf[0][ks], w2, acc1[0][nt], 0, 0, 0);
                acc1[1][nt] = __builtin_amdgcn_mfma_f32_16x16x32_bf16(xf[1][ks], w2, acc1[1][nt], 0, 0, 0);
            }
        }
        // leaky -> wave-private LDS [row=pair 0..31][col=ch 0..95, stride 104]
        #pragma unroll
        for (int nt = 0; nt < 6; ++nt) {
            int col = nt * 16 + l16;
            #pragma unroll
            for (int mt = 0; mt < 2; ++mt)
                #pragma unroll
                for (int r = 0; r < 4; ++r) {
                    float v = acc1[mt][nt][r];
                    v = fmaxf(v, 0.01f * v);
                    int row = mt * 16 + quad * 4 + r;
                    *(__bf16*)(hbase + row * 208 + col * 2) = (__bf16)v;
                }
        }
        // read back as A-frags (within-wave dependency; compiler waits lgkm)
        bf16x8 a2[2][3];
        #pragma unroll
        for (int mt = 0; mt < 2; ++mt)
            #pragma unroll
            for (int ks2 = 0; ks2 < 3; ++ks2)
                a2[mt][ks2] = *(const bf16x8*)(hbase +
                    (mt * 16 + l16) * 208 + ks2 * 64 + quad * 16);
        // GEMM2 half: K-chunk [96h, 96h+96)
        #pragma unroll
        for (int nt2 = 0; nt2 < 6; ++nt2) {
            #pragma unroll
            for (int ks2 = 0; ks2 < 3; ++ks2) {
                bf16x8 w = w1v[(nt2 * 6 + h * 3 + ks2) * 64 + lane];
                acc2[0][nt2] = __builtin_amdgcn_mfma_f32_16x16x32_bf16(a2[0][ks2], w, acc2[0][nt2], 0, 0, 0);
                acc2[1][nt2] = __builtin_amdgcn_mfma_f32_16x16x32_bf16(a2[1][ks2], w, acc2[1][nt2], 0, 0, 0);
            }
        }
        __syncthreads();   // rhythm: keep waves' weight streams coalesced
    }

    // ---- epilogue: leaky + dot(wout) + l16 butterfly + sigmoid ----
    const float* wout = (const float*)(ws + WS_WOUT);
    float part[2][4] = {{0.f, 0.f, 0.f, 0.f}, {0.f, 0.f, 0.f, 0.f}};
    #pragma unroll
    for (int nt2 = 0; nt2 < 6; ++nt2) {
        float wo = wout[nt2 * 16 + l16];
        #pragma unroll
        for (int mt = 0; mt < 2; ++mt)
            #pragma unroll
            for (int r = 0; r < 4; ++r) {
                float v = acc2[mt][nt2][r];
                v = fmaxf(v, 0.01f * v);
                part[mt][r] = fmaf(v, wo, part[mt][r]);
            }
    }
    #pragma unroll
    for (int off = 1; off < 16; off <<= 1)
        #pragma unroll
        for (int mt = 0; mt < 2; ++mt)
            #pragma unroll
            for (int r = 0; r < 4; ++r)
                part[mt][r] += __shfl_xor(part[mt][r], off, 64);
    // all lanes now hold their quad's 4 pair results
    float b0s = boutp[0];
    float sv[2][4];
    #pragma unroll
    for (int mt = 0; mt < 2; ++mt)
        #pragma unroll
        for (int r = 0; r < 4; ++r)
            sv[mt][r] = 1.f / (1.f + expf(-(part[mt][r] + b0s)));

    // direct column partial: sum over the 16 i's of this block per j
    #pragma unroll
    for (int mt = 0; mt < 2; ++mt) {
        float t = sv[mt][0] + sv[mt][1] + sv[mt][2] + sv[mt][3];
        t += __shfl_xor(t, 16, 64);
        t += __shfl_xor(t, 32, 64);
        if (lane == 0) atomicAdd(colsum + jb + mt, t);
    }
    // stores + mirror column contributions (dedup: skip if mirror cell is
    // direct-covered, i.e. col/8 >= 2*(row/16))
    if (l16 == 0) {
        #pragma unroll
        for (int mt = 0; mt < 2; ++mt) {
            int jcol = jb + mt;
            float4 m4 = {sv[mt][0], sv[mt][1], sv[mt][2], sv[mt][3]};
            *(float4*)(sim_out + jcol * NN + i0 + quad * 4) = m4;   // mirror row
            #pragma unroll
            for (int r = 0; r < 4; ++r) {
                int irow = i0 + quad * 4 + r;
                sim_out[irow * NN + jcol] = sv[mt][r];              // direct
                if (!((irow >> 3) >= 2 * (jcol >> 4)))
                    atomicAdd(colsum + irow, sv[mt][r]);
            }
        }
    }
}

// ---------------------------------------------------------------------------
// edge[i][j] = (sim + eye + 1e-6) / (colsum[j] + 1 + N*1e-6)
// ---------------------------------------------------------------------------
__global__ __launch_bounds__(256) void edge_kernel(
    const float* __restrict__ colsum, const float* __restrict__ sim,
    float* __restrict__ edge)
{
    int i = blockIdx.x;
    int jc = threadIdx.x << 2;
    float4 cs = *(const float4*)(colsum + jc);
    const float cadd = 1.0f + (float)NN * 1e-6f;
    float4 s = *(const float4*)(sim + i * NN + jc);
    float4 o;
    o.x = (s.x + (i == jc + 0 ? 1.f : 0.f) + 1e-6f) / (cs.x + cadd);
    o.y = (s.y + (i == jc + 1 ? 1.f : 0.f) + 1e-6f) / (cs.y + cadd);
    o.z = (s.z + (i == jc + 2 ? 1.f : 0.f) + 1e-6f) / (cs.z + cadd);
    o.w = (s.w + (i == jc + 3 ? 1.f : 0.f) + 1e-6f) / (cs.w + cadd);
    *(float4*)(edge + i * NN + jc) = o;
}

extern "C" void kernel_launch(void* const* d_in, const int* in_sizes, int n_in,
                              void* d_out, int out_size, void* d_ws, size_t ws_size,
                              hipStream_t stream)
{
    const float* feat = (const float*)d_in[0];
    const float* W0   = (const float*)d_in[1];
    const float* g0   = (const float*)d_in[2];
    const float* b0   = (const float*)d_in[3];
    const float* m0   = (const float*)d_in[4];
    const float* v0   = (const float*)d_in[5];
    const float* W1   = (const float*)d_in[6];
    const float* g1   = (const float*)d_in[7];
    const float* b1   = (const float*)d_in[8];
    const float* m1   = (const float*)d_in[9];
    const float* v1   = (const float*)d_in[10];
    const float* Wout = (const float*)d_in[11];
    const float* bout = (const float*)d_in[12];
    char* ws = (char*)d_ws;
    float* edge = (float*)d_out;
    float* sim  = edge + NN * NN;
    float* csum = (float*)(ws + WS_CSUM);

    prep_kernel<<<dim3(174), dim3(256), 0, stream>>>(
        W0, g0, b0, m0, v0, W1, g1, b1, m1, v1, Wout, ws);
    edgenet_main<<<dim3(4160), dim3(256), 0, stream>>>(feat, ws, bout, sim, csum);
    edge_kernel<<<dim3(1024), dim3(256), 0, stream>>>(csum, sim, edge);
}

// Round 6
// 183.962 us; speedup vs baseline: 1.7842x; 1.7842x over previous
//
#include <hip/hip_runtime.h>
#include <hip/hip_bf16.h>
#include <math.h>

typedef float v4f __attribute__((ext_vector_type(4)));
typedef __bf16 bf16x8 __attribute__((ext_vector_type(8)));

#define NN   1024
#define INF  128
#define H0C  192
#define H1C  96

// ws byte offsets
#define WS_W0BF   0        // 24576 bf16 = 49152 B (16x16x32 B-frag order, BN0 scale folded)
#define WS_W1BF   49152    // 18432 bf16 = 36864 B (16x16x32 B-frag order, BN1 scale folded)
#define WS_BN0B   86016    // 192 f32 folded bias
#define WS_BN1B   86784    // 96 f32 folded bias
#define WS_WOUT   87168    // 96 f32
#define WS_PART   91648    // 16*1024 f32 column partial sums

// ---------------------------------------------------------------------------
// Prep: swizzle weights into MFMA B-fragment order (bf16), BN scale folded,
// bias folded separately.
// B-frag (16x16x32): lane holds B[k=quad*8+j][n=lane&15],
// flat [(ntile*KS+ks)*64 + lane]*8 + j.   [validated rounds 2-5]
// ---------------------------------------------------------------------------
__global__ __launch_bounds__(256) void prep_kernel(
    const float* __restrict__ W0, const float* __restrict__ g0,
    const float* __restrict__ b0, const float* __restrict__ m0,
    const float* __restrict__ v0, const float* __restrict__ W1,
    const float* __restrict__ g1, const float* __restrict__ b1,
    const float* __restrict__ m1, const float* __restrict__ v1,
    const float* __restrict__ Wout, char* __restrict__ ws)
{
    int e = blockIdx.x * 256 + threadIdx.x;
    __bf16* w0bf = (__bf16*)(ws + WS_W0BF);
    __bf16* w1bf = (__bf16*)(ws + WS_W1BF);
    float* bn0b = (float*)(ws + WS_BN0B);
    float* bn1b = (float*)(ws + WS_BN1B);
    float* wout = (float*)(ws + WS_WOUT);
    if (e < 24576) {                       // W0: 12 ntiles x 4 ksteps
        int j = e & 7, lane = (e >> 3) & 63, t = e >> 9;
        int ks = t & 3, nt = t >> 2;
        int c = nt * 16 + (lane & 15);               // n = H0 channel
        int k = ks * 32 + ((lane >> 4) << 3) + j;    // k = input feature
        float s = g0[c] * rsqrtf(v0[c] + 1e-5f);
        w0bf[e] = (__bf16)(W0[c * INF + k] * s);
    } else if (e < 43008) {                // W1: 6 ntiles x 6 ksteps
        int e2 = e - 24576;
        int j = e2 & 7, lane = (e2 >> 3) & 63, t = e2 >> 9;
        int ks = t % 6, nt = t / 6;
        int c = nt * 16 + (lane & 15);               // n = H1 channel
        int k = ks * 32 + ((lane >> 4) << 3) + j;    // k = H0 channel
        float s = g1[c] * rsqrtf(v1[c] + 1e-5f);
        w1bf[e2] = (__bf16)(W1[c * H0C + k] * s);
    } else if (e < 43200) {                // BN0 folded bias
        int c = e - 43008;
        float s = g0[c] * rsqrtf(v0[c] + 1e-5f);
        bn0b[c] = b0[c] - m0[c] * s;
    } else if (e < 43296) {                // BN1 folded bias
        int c = e - 43200;
        float s = g1[c] * rsqrtf(v1[c] + 1e-5f);
        bn1b[c] = b1[c] - m1[c] * s;
    } else if (e < 43392) {                // Wout copy
        wout[e - 43296] = Wout[e - 43296];
    }
}

// ---------------------------------------------------------------------------
// Main fused kernel. Block = 4 waves, tile 16 i x 8 j = 128 pairs; wave w
// owns j-columns jb=8bj+2w, jb+1 (32 pairs, 2 mtiles of 16 in the j dim).
// - X fragments generated directly in registers (no X LDS phase).
// - GEMM1 split into two 96-channel halves (acc1 = 48 regs, not 96).
// - H0 half round-trips through WAVE-PRIVATE LDS (32 x 104 bf16) to
//   transpose C-layout -> A-frag; K=32 MFMA for BOTH layers.
// - __syncthreads() per half = rhythm barrier only (keeps the 4 waves'
//   identical weight-load streams time-coalesced for L1 reuse; R2 vs R3/R4
//   evidence).
// - Epilogue: NO atomics (R5's fatal flaw). Butterfly reduce + cndmask
//   select + one cross-quad shfl transpose; all 64 lanes store exactly one
//   value: quads 0-1 direct sim[i][j], quads 2-3 coalesced mirror sim[j][i].
// Symmetry: triangular tiles bj >= 2*bi (4160 blocks).
// ---------------------------------------------------------------------------
__global__ __launch_bounds__(256, 3) void edgenet_main(
    const float* __restrict__ feat, const char* __restrict__ ws,
    const float* __restrict__ boutp, float* __restrict__ sim_out)
{
    __shared__ __align__(16) char smem[26624];   // 4 waves * 32 rows * 208 B
    const int tid = threadIdx.x;
    const int lane = tid & 63;
    const int wave = tid >> 6;
    const int l16 = lane & 15;
    const int quad = lane >> 4;

    // decode triangular tile id -> (bi, bj): cum(bi) = bi*(129-bi)  [R2-verified]
    const int id = blockIdx.x;
    int bi = (int)((129.0f - sqrtf(16641.0f - 4.0f * (float)id)) * 0.5f);
    while (bi > 0 && bi * (129 - bi) > id) --bi;
    while ((bi + 1) * (128 - bi) <= id) ++bi;
    const int bj = 2 * bi + (id - bi * (129 - bi));
    const int i0 = bi << 4;
    const int jb = (bj << 3) + wave * 2;
    char* hbase = smem + wave * 6656;

    // ---- X A-fragments in registers: xf[mt][ks], lane = X[pair=l16][32ks+8q+j]
    bf16x8 xf[2][4];
    #pragma unroll
    for (int ks = 0; ks < 4; ++ks) {
        const float* fi = feat + (i0 + l16) * INF + ks * 32 + quad * 8;
        float4 a0 = *(const float4*)fi;
        float4 a1 = *(const float4*)(fi + 4);
        #pragma unroll
        for (int mt = 0; mt < 2; ++mt) {
            const float* fj = feat + (jb + mt) * INF + ks * 32 + quad * 8;
            float4 q0 = *(const float4*)fj;
            float4 q1 = *(const float4*)(fj + 4);
            bf16x8 x;
            x[0] = (__bf16)fabsf(a0.x - q0.x);
            x[1] = (__bf16)fabsf(a0.y - q0.y);
            x[2] = (__bf16)fabsf(a0.z - q0.z);
            x[3] = (__bf16)fabsf(a0.w - q0.w);
            x[4] = (__bf16)fabsf(a1.x - q1.x);
            x[5] = (__bf16)fabsf(a1.y - q1.y);
            x[6] = (__bf16)fabsf(a1.z - q1.z);
            x[7] = (__bf16)fabsf(a1.w - q1.w);
            xf[mt][ks] = x;
        }
    }

    const bf16x8* w0v = (const bf16x8*)(ws + WS_W0BF);
    const bf16x8* w1v = (const bf16x8*)(ws + WS_W1BF);
    const float* bn0b = (const float*)(ws + WS_BN0B);
    const float* bn1b = (const float*)(ws + WS_BN1B);

    // ---- acc2 init with bn1 bias (col = ch_out = 16nt2+l16, bcast over rows)
    v4f acc2[2][6];
    #pragma unroll
    for (int nt2 = 0; nt2 < 6; ++nt2) {
        float bb = bn1b[nt2 * 16 + l16];
        acc2[0][nt2] = (v4f){bb, bb, bb, bb};
        acc2[1][nt2] = acc2[0][nt2];
    }

    // ---- two 96-channel halves: GEMM1-half -> leaky -> LDS -> GEMM2-half ----
    #pragma unroll 1
    for (int h = 0; h < 2; ++h) {
        // GEMM1 half: channels [96h, 96h+96)
        v4f acc1[2][6];
        #pragma unroll
        for (int nt = 0; nt < 6; ++nt) {
            float bb = bn0b[h * 96 + nt * 16 + l16];
            v4f c0 = (v4f){bb, bb, bb, bb};
            bf16x8 w = w0v[((h * 6 + nt) * 4 + 0) * 64 + lane];
            acc1[0][nt] = __builtin_amdgcn_mfma_f32_16x16x32_bf16(xf[0][0], w, c0, 0, 0, 0);
            acc1[1][nt] = __builtin_amdgcn_mfma_f32_16x16x32_bf16(xf[1][0], w, c0, 0, 0, 0);
            #pragma unroll
            for (int ks = 1; ks < 4; ++ks) {
                bf16x8 w2 = w0v[((h * 6 + nt) * 4 + ks) * 64 + lane];
                acc1[0][nt] = __builtin_amdgcn_mfma_f32_16x16x32_bf16(xf[0][ks], w2, acc1[0][nt], 0, 0, 0);
                acc1[1][nt] = __builtin_amdgcn_mfma_f32_16x16x32_bf16(xf[1][ks], w2, acc1[1][nt], 0, 0, 0);
            }
        }
        // leaky -> wave-private LDS [row=pair 0..31][col=ch 0..95, stride 104]
        #pragma unroll
        for (int nt = 0; nt < 6; ++nt) {
            int col = nt * 16 + l16;
            #pragma unroll
            for (int mt = 0; mt < 2; ++mt)
                #pragma unroll
                for (int r = 0; r < 4; ++r) {
                    float v = acc1[mt][nt][r];
                    v = fmaxf(v, 0.01f * v);
                    int row = mt * 16 + quad * 4 + r;
                    *(__bf16*)(hbase + row * 208 + col * 2) = (__bf16)v;
                }
        }
        // read back as A-frags (within-wave dependency; compiler waits lgkm)
        bf16x8 a2[2][3];
        #pragma unroll
        for (int mt = 0; mt < 2; ++mt)
            #pragma unroll
            for (int ks2 = 0; ks2 < 3; ++ks2)
                a2[mt][ks2] = *(const bf16x8*)(hbase +
                    (mt * 16 + l16) * 208 + ks2 * 64 + quad * 16);
        // GEMM2 half: K-chunk [96h, 96h+96)
        #pragma unroll
        for (int nt2 = 0; nt2 < 6; ++nt2) {
            #pragma unroll
            for (int ks2 = 0; ks2 < 3; ++ks2) {
                bf16x8 w = w1v[(nt2 * 6 + h * 3 + ks2) * 64 + lane];
                acc2[0][nt2] = __builtin_amdgcn_mfma_f32_16x16x32_bf16(a2[0][ks2], w, acc2[0][nt2], 0, 0, 0);
                acc2[1][nt2] = __builtin_amdgcn_mfma_f32_16x16x32_bf16(a2[1][ks2], w, acc2[1][nt2], 0, 0, 0);
            }
        }
        __syncthreads();   // rhythm: keep waves' weight streams coalesced
    }

    // ---- epilogue: leaky + dot(wout) + l16 butterfly ----
    const float* wout = (const float*)(ws + WS_WOUT);
    float part[2][4] = {{0.f, 0.f, 0.f, 0.f}, {0.f, 0.f, 0.f, 0.f}};
    #pragma unroll
    for (int nt2 = 0; nt2 < 6; ++nt2) {
        float wo = wout[nt2 * 16 + l16];
        #pragma unroll
        for (int mt = 0; mt < 2; ++mt)
            #pragma unroll
            for (int r = 0; r < 4; ++r) {
                float v = acc2[mt][nt2][r];
                v = fmaxf(v, 0.01f * v);
                part[mt][r] = fmaf(v, wo, part[mt][r]);
            }
    }
    #pragma unroll
    for (int off = 1; off < 16; off <<= 1)
        #pragma unroll
        for (int mt = 0; mt < 2; ++mt)
            #pragma unroll
            for (int r = 0; r < 4; ++r)
                part[mt][r] += __shfl_xor(part[mt][r], off, 64);

    // ---- transpose via cndmask-select + one shfl; all 64 lanes store once --
    // lane (q,l16) holds part[mt][r] = logit(pair i0+4q+r, jb+mt), replicated
    // over l16. Select own r=l16&3, then pull from quad l16>>2 so every lane
    // ends with the value for pair (i0+l16, jb+(quad&1)).
    int rsel = l16 & 3;
    float ya0 = (rsel & 2) ? ((rsel & 1) ? part[0][3] : part[0][2])
                           : ((rsel & 1) ? part[0][1] : part[0][0]);
    float ya1 = (rsel & 2) ? ((rsel & 1) ? part[1][3] : part[1][2])
                           : ((rsel & 1) ? part[1][1] : part[1][0]);
    int src = ((l16 >> 2) << 4) | l16;
    float z0 = __shfl(ya0, src, 64);
    float z1 = __shfl(ya1, src, 64);
    float z = (quad & 1) ? z1 : z0;
    float sv = 1.f / (1.f + expf(-(z + boutp[0])));
    if (quad < 2)
        sim_out[(i0 + l16) * NN + jb + quad] = sv;          // direct (strided)
    else
        sim_out[(jb + (quad - 2)) * NN + i0 + l16] = sv;    // mirror (64B coalesced)
}

// ---------------------------------------------------------------------------
// Column partial sums: grid(16 jgroups, 16 igroups).
// ---------------------------------------------------------------------------
__global__ __launch_bounds__(256) void colsum_kernel(
    const float* __restrict__ sim, float* __restrict__ part)
{
    __shared__ float red[4][64];
    int jl = threadIdx.x & 63;
    int ig = threadIdx.x >> 6;
    int j = blockIdx.x * 64 + jl;
    int ibase = blockIdx.y * 64 + ig * 16;
    float s = 0.f;
    #pragma unroll
    for (int r = 0; r < 16; ++r)
        s += sim[(ibase + r) * NN + j];
    red[ig][jl] = s;
    __syncthreads();
    if (ig == 0) {
        float t = red[0][jl] + red[1][jl] + red[2][jl] + red[3][jl];
        part[blockIdx.y * NN + j] = t;
    }
}

// ---------------------------------------------------------------------------
// Fused finalize+edge: block = one i row; each thread handles 4 j's.
// colsum recomputed per thread from the 64 KB part array (L2-hot).
// ---------------------------------------------------------------------------
__global__ __launch_bounds__(256) void edge_kernel(
    const float* __restrict__ partsum, const float* __restrict__ sim,
    float* __restrict__ edge)
{
    int i = blockIdx.x;
    int jc = threadIdx.x << 2;
    float4 t = {0.f, 0.f, 0.f, 0.f};
    #pragma unroll
    for (int p = 0; p < 16; ++p) {
        float4 q = *(const float4*)(partsum + p * NN + jc);
        t.x += q.x; t.y += q.y; t.z += q.z; t.w += q.w;
    }
    const float cadd = 1.0f + (float)NN * 1e-6f;
    float4 s = *(const float4*)(sim + i * NN + jc);
    float4 o;
    o.x = (s.x + (i == jc + 0 ? 1.f : 0.f) + 1e-6f) / (t.x + cadd);
    o.y = (s.y + (i == jc + 1 ? 1.f : 0.f) + 1e-6f) / (t.y + cadd);
    o.z = (s.z + (i == jc + 2 ? 1.f : 0.f) + 1e-6f) / (t.z + cadd);
    o.w = (s.w + (i == jc + 3 ? 1.f : 0.f) + 1e-6f) / (t.w + cadd);
    *(float4*)(edge + i * NN + jc) = o;
}

extern "C" void kernel_launch(void* const* d_in, const int* in_sizes, int n_in,
                              void* d_out, int out_size, void* d_ws, size_t ws_size,
                              hipStream_t stream)
{
    const float* feat = (const float*)d_in[0];
    const float* W0   = (const float*)d_in[1];
    const float* g0   = (const float*)d_in[2];
    const float* b0   = (const float*)d_in[3];
    const float* m0   = (const float*)d_in[4];
    const float* v0   = (const float*)d_in[5];
    const float* W1   = (const float*)d_in[6];
    const float* g1   = (const float*)d_in[7];
    const float* b1   = (const float*)d_in[8];
    const float* m1   = (const float*)d_in[9];
    const float* v1   = (const float*)d_in[10];
    const float* Wout = (const float*)d_in[11];
    const float* bout = (const float*)d_in[12];
    char* ws = (char*)d_ws;
    float* edge = (float*)d_out;
    float* sim  = edge + NN * NN;
    float* part = (float*)(ws + WS_PART);

    prep_kernel<<<dim3(170), dim3(256), 0, stream>>>(
        W0, g0, b0, m0, v0, W1, g1, b1, m1, v1, Wout, ws);
    edgenet_main<<<dim3(4160), dim3(256), 0, stream>>>(feat, ws, bout, sim);
    colsum_kernel<<<dim3(16, 16), dim3(256), 0, stream>>>(sim, part);
    edge_kernel<<<dim3(1024), dim3(256), 0, stream>>>(part, sim, edge);
}

// Round 7
// 154.081 us; speedup vs baseline: 2.1302x; 1.1939x over previous
//
#include <hip/hip_runtime.h>
#include <hip/hip_bf16.h>
#include <math.h>

typedef float v4f __attribute__((ext_vector_type(4)));
typedef __bf16 bf16x8 __attribute__((ext_vector_type(8)));
typedef __bf16 bf16x4 __attribute__((ext_vector_type(4)));

#define NN   1024
#define INF  128
#define H0C  192
#define H1C  96

// ws byte offsets
#define WS_W0BF   0        // 24576 bf16 (A-frag order, BN0 scale folded)
#define WS_W1BF   49152    // 18432 bf16 (A-frag order, BN1 scale folded)
#define WS_BN0SW  86016    // 192 f32: [q][cm][r] = bias0[16cm+4q+r]
#define WS_BN1SW  86784    // 96 f32:  [q][mt][r] = bias1[16mt+4q+r]
#define WS_WOUTSW 87168    // 96 f32:  [q][mt][r] = wout[16mt+4q+r]
#define WS_PART   91648    // 16*1024 f32 column partial sums

// ---------------------------------------------------------------------------
// Prep. A-frag (16x16x32): lane holds A[m=l16][k=quad*8+j] (same storage as
// the B-frag by m/k symmetry; layout validated rounds 2-6).
// flat [(mtile*KS+ks)*64 + lane]*8 + j, m = channel, k = input dim.
// Biases and wout pre-swizzled to C-layout register order [q][mt][r].
// ---------------------------------------------------------------------------
__global__ __launch_bounds__(256) void prep_kernel(
    const float* __restrict__ W0, const float* __restrict__ g0,
    const float* __restrict__ b0, const float* __restrict__ m0,
    const float* __restrict__ v0, const float* __restrict__ W1,
    const float* __restrict__ g1, const float* __restrict__ b1,
    const float* __restrict__ m1, const float* __restrict__ v1,
    const float* __restrict__ Wout, char* __restrict__ ws)
{
    int e = blockIdx.x * 256 + threadIdx.x;
    __bf16* w0bf = (__bf16*)(ws + WS_W0BF);
    __bf16* w1bf = (__bf16*)(ws + WS_W1BF);
    float* bn0sw = (float*)(ws + WS_BN0SW);
    float* bn1sw = (float*)(ws + WS_BN1SW);
    float* woutsw = (float*)(ws + WS_WOUTSW);
    if (e < 24576) {                       // W0: 12 mtiles x 4 ksteps
        int j = e & 7, lane = (e >> 3) & 63, t = e >> 9;
        int ks = t & 3, mt = t >> 2;
        int c = mt * 16 + (lane & 15);               // m = H0 channel
        int k = ks * 32 + ((lane >> 4) << 3) + j;    // k = input feature
        float s = g0[c] * rsqrtf(v0[c] + 1e-5f);
        w0bf[e] = (__bf16)(W0[c * INF + k] * s);
    } else if (e < 43008) {                // W1: 6 mtiles x 6 ksteps
        int e2 = e - 24576;
        int j = e2 & 7, lane = (e2 >> 3) & 63, t = e2 >> 9;
        int ks = t % 6, mt = t / 6;
        int c = mt * 16 + (lane & 15);               // m = H1 channel
        int k = ks * 32 + ((lane >> 4) << 3) + j;    // k = H0 channel
        float s = g1[c] * rsqrtf(v1[c] + 1e-5f);
        w1bf[e2] = (__bf16)(W1[c * H0C + k] * s);
    } else if (e < 43200) {                // bn0 bias swizzled [q][cm][r]
        int e3 = e - 43008;
        int q = e3 / 48, rem = e3 % 48, cm = rem >> 2, r = rem & 3;
        int c = cm * 16 + q * 4 + r;
        float s = g0[c] * rsqrtf(v0[c] + 1e-5f);
        bn0sw[e3] = b0[c] - m0[c] * s;
    } else if (e < 43296) {                // bn1 bias swizzled [q][mt][r]
        int e4 = e - 43200;
        int q = e4 / 24, rem = e4 % 24, mt = rem >> 2, r = rem & 3;
        int c = mt * 16 + q * 4 + r;
        float s = g1[c] * rsqrtf(v1[c] + 1e-5f);
        bn1sw[e4] = b1[c] - m1[c] * s;
    } else if (e < 43392) {                // wout swizzled [q][mt][r]
        int e5 = e - 43296;
        int q = e5 / 24, rem = e5 % 24, mt = rem >> 2, r = rem & 3;
        woutsw[e5] = Wout[mt * 16 + q * 4 + r];
    }
}

// ---------------------------------------------------------------------------
// Main kernel, channel-split dataflow. Block = 4 waves, 128 pairs (16i x 8j).
// MFMA roles: A = weights (channels in M), B = pairs (N). Fixes the weight-
// bandwidth bind of R3/R4/R6: layer-1 weight traffic = 12 KB/wave (not 49),
// amortized over all 128 pairs.
//  - X staged once in LDS [pair][feat] (34.8 KB), stride 272 B.
//  - Layer1: wave w owns ch mtiles {3w..3w+2}; acc1[3][8]; C row=ch, col=pair.
//  - H0 epilogue: leaky + pack 4ch -> ONE ds_write_b64/lane/tile (24 total)
//    into H0 [pair][ch] (51.2 KB, stride 400 B, overlays dead X).
//  - Layer2: wave owns 2 pair-ntiles (32 pairs); H0 rows ARE the B-frags.
//  - Epilogue: dot(wout-swizzled) over 6 mt, butterfly xor16/32 across quads,
//    sigmoid; 64 lanes store once (quads 0-1 direct, 2-3 coalesced mirror).
// Symmetry: triangular tiles bj >= 2*bi (4160 blocks).
// ---------------------------------------------------------------------------
__global__ __launch_bounds__(256, 3) void edgenet_main(
    const float* __restrict__ feat, const char* __restrict__ ws,
    const float* __restrict__ boutp, float* __restrict__ sim_out)
{
    __shared__ __align__(16) char smem[51200];   // H0 [128][400B]; X overlays
    const int tid = threadIdx.x;
    const int lane = tid & 63;
    const int wave = tid >> 6;
    const int l16 = lane & 15;
    const int quad = lane >> 4;

    // decode triangular tile id -> (bi, bj): cum(bi) = bi*(129-bi)  [R2-verified]
    const int id = blockIdx.x;
    int bi = (int)((129.0f - sqrtf(16641.0f - 4.0f * (float)id)) * 0.5f);
    while (bi > 0 && bi * (129 - bi) > id) --bi;
    while ((bi + 1) * (128 - bi) <= id) ++bi;
    const int bj = 2 * bi + (id - bi * (129 - bi));
    const int i0 = bi << 4;
    const int j0 = bj << 3;
    const int jb = j0 + wave * 2;

    // ---- Phase 1: X[p][f] = |f_i - f_j| bf16 -> LDS, stride 272 B ----
    #pragma unroll
    for (int it = 0; it < 8; ++it) {
        int c = it * 256 + tid;        // chunk id: 16 chunks (of 8 feats) per pair
        int p = c >> 4;                // pair = jj*16 + ii
        int f0 = (c & 15) << 3;
        int ii = p & 15, jj = p >> 4;
        const float* fi = feat + (i0 + ii) * INF + f0;
        const float* fj = feat + (j0 + jj) * INF + f0;
        float4 a0 = *(const float4*)fi;
        float4 a1 = *(const float4*)(fi + 4);
        float4 q0 = *(const float4*)fj;
        float4 q1 = *(const float4*)(fj + 4);
        bf16x8 x;
        x[0] = (__bf16)fabsf(a0.x - q0.x);
        x[1] = (__bf16)fabsf(a0.y - q0.y);
        x[2] = (__bf16)fabsf(a0.z - q0.z);
        x[3] = (__bf16)fabsf(a0.w - q0.w);
        x[4] = (__bf16)fabsf(a1.x - q1.x);
        x[5] = (__bf16)fabsf(a1.y - q1.y);
        x[6] = (__bf16)fabsf(a1.z - q1.z);
        x[7] = (__bf16)fabsf(a1.w - q1.w);
        *(bf16x8*)(smem + p * 272 + f0 * 2) = x;
    }
    __syncthreads();

    const bf16x8* w0v = (const bf16x8*)(ws + WS_W0BF);
    const bf16x8* w1v = (const bf16x8*)(ws + WS_W1BF);
    const float* bn0sw = (const float*)(ws + WS_BN0SW);
    const float* bn1sw = (const float*)(ws + WS_BN1SW);

    // ---- Layer 1: wave owns channel mtiles cm = 3*wave + mt, all 128 pairs --
    v4f acc1[3][8];
    #pragma unroll
    for (int mt = 0; mt < 3; ++mt) {
        v4f bb = *(const v4f*)(bn0sw + (quad * 12 + wave * 3 + mt) * 4);
        #pragma unroll
        for (int nt = 0; nt < 8; ++nt)
            acc1[mt][nt] = bb;
    }
    #pragma unroll
    for (int ks = 0; ks < 4; ++ks) {
        bf16x8 xk[8];
        #pragma unroll
        for (int nt = 0; nt < 8; ++nt)
            xk[nt] = *(const bf16x8*)(smem + (nt * 16 + l16) * 272 + ks * 64 + quad * 16);
        #pragma unroll
        for (int mt = 0; mt < 3; ++mt) {
            bf16x8 w = w0v[((wave * 3 + mt) * 4 + ks) * 64 + lane];
            #pragma unroll
            for (int nt = 0; nt < 8; ++nt)
                acc1[mt][nt] = __builtin_amdgcn_mfma_f32_16x16x32_bf16(
                    w, xk[nt], acc1[mt][nt], 0, 0, 0);
        }
    }
    __syncthreads();   // all X reads done; H0 may overlay

    // ---- H0 write: leaky + pack 4 consecutive channels -> ds_write_b64 ----
    #pragma unroll
    for (int mt = 0; mt < 3; ++mt) {
        int chb = (wave * 3 + mt) * 16 + quad * 4;   // first of 4 channels
        #pragma unroll
        for (int nt = 0; nt < 8; ++nt) {
            bf16x4 pk;
            #pragma unroll
            for (int r = 0; r < 4; ++r) {
                float v = acc1[mt][nt][r];
                v = fmaxf(v, 0.01f * v);
                pk[r] = (__bf16)v;
            }
            *(bf16x4*)(smem + (nt * 16 + l16) * 400 + chb * 2) = pk;
        }
    }
    __syncthreads();   // H0 complete (cross-wave channels)

    // ---- Layer 2: wave owns pair ntiles {2w, 2w+1}; H0 rows are B-frags ----
    v4f acc2[6][2];
    #pragma unroll
    for (int mt = 0; mt < 6; ++mt) {
        v4f bb = *(const v4f*)(bn1sw + (quad * 6 + mt) * 4);
        acc2[mt][0] = bb;
        acc2[mt][1] = bb;
    }
    #pragma unroll
    for (int ks = 0; ks < 6; ++ks) {
        bf16x8 h0, h1;
        h0 = *(const bf16x8*)(smem + ((2 * wave + 0) * 16 + l16) * 400 + ks * 64 + quad * 16);
        h1 = *(const bf16x8*)(smem + ((2 * wave + 1) * 16 + l16) * 400 + ks * 64 + quad * 16);
        #pragma unroll
        for (int mt = 0; mt < 6; ++mt) {
            bf16x8 w = w1v[(mt * 6 + ks) * 64 + lane];
            acc2[mt][0] = __builtin_amdgcn_mfma_f32_16x16x32_bf16(w, h0, acc2[mt][0], 0, 0, 0);
            acc2[mt][1] = __builtin_amdgcn_mfma_f32_16x16x32_bf16(w, h1, acc2[mt][1], 0, 0, 0);
        }
    }

    // ---- epilogue: leaky + dot(wout) + cross-quad butterfly + sigmoid ----
    const float* woutsw = (const float*)(ws + WS_WOUTSW);
    float part[2] = {0.f, 0.f};
    #pragma unroll
    for (int mt = 0; mt < 6; ++mt) {
        v4f wo = *(const v4f*)(woutsw + (quad * 6 + mt) * 4);
        #pragma unroll
        for (int t = 0; t < 2; ++t)
            #pragma unroll
            for (int r = 0; r < 4; ++r) {
                float v = acc2[mt][t][r];
                v = fmaxf(v, 0.01f * v);
                part[t] = fmaf(v, wo[r], part[t]);
            }
    }
    #pragma unroll
    for (int t = 0; t < 2; ++t) {
        part[t] += __shfl_xor(part[t], 16, 64);
        part[t] += __shfl_xor(part[t], 32, 64);
    }
    // lane (q,l16) now holds full logits for pair (i0+l16, jb+t), t=0,1,
    // replicated across quads. Each lane stores exactly one value.
    float z = (quad & 1) ? part[1] : part[0];
    float sv = 1.f / (1.f + expf(-(z + boutp[0])));
    if (quad < 2)
        sim_out[(i0 + l16) * NN + jb + (quad & 1)] = sv;        // direct
    else
        sim_out[(jb + (quad & 1)) * NN + i0 + l16] = sv;        // mirror, 64B runs
}

// ---------------------------------------------------------------------------
// Column partial sums: grid(16 jgroups, 16 igroups).
// ---------------------------------------------------------------------------
__global__ __launch_bounds__(256) void colsum_kernel(
    const float* __restrict__ sim, float* __restrict__ part)
{
    __shared__ float red[4][64];
    int jl = threadIdx.x & 63;
    int ig = threadIdx.x >> 6;
    int j = blockIdx.x * 64 + jl;
    int ibase = blockIdx.y * 64 + ig * 16;
    float s = 0.f;
    #pragma unroll
    for (int r = 0; r < 16; ++r)
        s += sim[(ibase + r) * NN + j];
    red[ig][jl] = s;
    __syncthreads();
    if (ig == 0) {
        float t = red[0][jl] + red[1][jl] + red[2][jl] + red[3][jl];
        part[blockIdx.y * NN + j] = t;
    }
}

// ---------------------------------------------------------------------------
// Fused finalize+edge: block = one i row; thread handles 4 j's.
// ---------------------------------------------------------------------------
__global__ __launch_bounds__(256) void edge_kernel(
    const float* __restrict__ partsum, const float* __restrict__ sim,
    float* __restrict__ edge)
{
    int i = blockIdx.x;
    int jc = threadIdx.x << 2;
    float4 t = {0.f, 0.f, 0.f, 0.f};
    #pragma unroll
    for (int p = 0; p < 16; ++p) {
        float4 q = *(const float4*)(partsum + p * NN + jc);
        t.x += q.x; t.y += q.y; t.z += q.z; t.w += q.w;
    }
    const float cadd = 1.0f + (float)NN * 1e-6f;
    float4 s = *(const float4*)(sim + i * NN + jc);
    float4 o;
    o.x = (s.x + (i == jc + 0 ? 1.f : 0.f) + 1e-6f) / (t.x + cadd);
    o.y = (s.y + (i == jc + 1 ? 1.f : 0.f) + 1e-6f) / (t.y + cadd);
    o.z = (s.z + (i == jc + 2 ? 1.f : 0.f) + 1e-6f) / (t.z + cadd);
    o.w = (s.w + (i == jc + 3 ? 1.f : 0.f) + 1e-6f) / (t.w + cadd);
    *(float4*)(edge + i * NN + jc) = o;
}

extern "C" void kernel_launch(void* const* d_in, const int* in_sizes, int n_in,
                              void* d_out, int out_size, void* d_ws, size_t ws_size,
                              hipStream_t stream)
{
    const float* feat = (const float*)d_in[0];
    const float* W0   = (const float*)d_in[1];
    const float* g0   = (const float*)d_in[2];
    const float* b0   = (const float*)d_in[3];
    const float* m0   = (const float*)d_in[4];
    const float* v0   = (const float*)d_in[5];
    const float* W1   = (const float*)d_in[6];
    const float* g1   = (const float*)d_in[7];
    const float* b1   = (const float*)d_in[8];
    const float* m1   = (const float*)d_in[9];
    const float* v1   = (const float*)d_in[10];
    const float* Wout = (const float*)d_in[11];
    const float* bout = (const float*)d_in[12];
    char* ws = (char*)d_ws;
    float* edge = (float*)d_out;
    float* sim  = edge + NN * NN;
    float* part = (float*)(ws + WS_PART);

    prep_kernel<<<dim3(170), dim3(256), 0, stream>>>(
        W0, g0, b0, m0, v0, W1, g1, b1, m1, v1, Wout, ws);
    edgenet_main<<<dim3(4160), dim3(256), 0, stream>>>(feat, ws, bout, sim);
    colsum_kernel<<<dim3(16, 16), dim3(256), 0, stream>>>(sim, part);
    edge_kernel<<<dim3(1024), dim3(256), 0, stream>>>(part, sim, edge);
}